// Round 14
// baseline (2916.298 us; speedup 1.0000x reference)
//
#include <hip/hip_runtime.h>
#include <math.h>

#define BS     16
#define NB     4
#define BB     64      // BS*NB
#define DD     512
#define VV     32000
#define TSTEPS 16
#define EOSTOK 2
#define NEGF   (-1e32f)
#define VT     64
#define NVT    (VV / VT)   // 500

__device__ __forceinline__ bool better(float av, int ai, float bv, int bi_) {
    return (av > bv) || (av == bv && ai < bi_);
}

// async global->LDS staging, no VGPR round-trip (gfx950)
__device__ __forceinline__ void glds4(const float* src, float* dst) {
    __builtin_amdgcn_global_load_lds((const __attribute__((address_space(1))) void*)src,
                                     (__attribute__((address_space(3))) void*)dst, 4, 0, 0);
}
__device__ __forceinline__ void glds16(const float* src, float* dst) {
    __builtin_amdgcn_global_load_lds((const __attribute__((address_space(1))) void*)src,
                                     (__attribute__((address_space(3))) void*)dst, 16, 0, 0);
}

// ---------------------------------------------------------------- init (fp32 states)
__global__ void init_kernel(const int* __restrict__ inputs,
                            const float* __restrict__ h0, const float* __restrict__ c0,
                            float* __restrict__ h0s, float* __restrict__ c0s,
                            float* __restrict__ h1s, float* __restrict__ c1s,
                            int* __restrict__ tokens, int* __restrict__ pidx,
                            int* __restrict__ fin, float* __restrict__ lp,
                            int* __restrict__ bo)
{
    int tid = blockIdx.x * blockDim.x + threadIdx.x;
    int total = BB * DD;
    for (int i = tid; i < total; i += gridDim.x * blockDim.x) {
        int b = i / DD;
        int d = i % DD;
        int src0 = 0 * BS * DD + (b >> 2) * DD + d;
        int src1 = 1 * BS * DD + (b >> 2) * DD + d;
        h0s[i] = h0[src0];
        c0s[i] = c0[src0];
        h1s[i] = h0[src1];
        c1s[i] = c0[src1];
    }
    if (tid < BB) {
        tokens[tid] = inputs[tid >> 2];
        pidx[tid]   = tid;
        fin[tid]    = 0;
        lp[tid]     = 0.0f;
        bo[0 * BB + tid] = inputs[tid >> 2];
        for (int r = 1; r <= TSTEPS; r++) bo[r * BB + tid] = 0;
    }
}

// ---------------------------------------------------------------- LSTM: one block per output unit j
// 512 blocks x 256 threads; thread = (b 0..63, gate 0..3).
// 16 K-chunks of 64, double-buffered U staging (stage ch+1 issued before compute ch).
// Chain assignment (global k%4, ascending k) identical to R13 -> bitwise-identical output.
__global__ __launch_bounds__(256) void lstm_kernel(
    const float* __restrict__ xbase, const int* __restrict__ xrow,
    const float* __restrict__ hsrc,  const float* __restrict__ csrc,
    const int* __restrict__ prow,
    float* __restrict__ hdst, float* __restrict__ cdst,
    const float* __restrict__ Wih, const float* __restrict__ Whh,
    const float* __restrict__ bias)
{
    __shared__ float U[2][64][65];  // dbuf; bank (b+k)%32, 2-way max; row 260B holds 256B wave-write
    __shared__ float Wl[4][1024];   // all weight rows for this j (16 KB)
    __shared__ double Z[4][64];
    __shared__ int rows_s[64], prows_s[64];
    int tid = threadIdx.x;
    int j = blockIdx.x;
    int b = tid & 63;
    int g = tid >> 6;
    int lane = tid & 63;
    int w = tid >> 6;               // wave id 0..3

    // ---- W burst: 16 KB via width-16 async copies (4 per thread), fully concurrent
    #pragma unroll
    for (int i = 0; i < 4; i++) {
        int s0 = i * 256 + w * 64;              // wave-uniform float4 slot base (0..1023)
        int gg = s0 >> 8;                       // gate
        int hh = (s0 >> 7) & 1;                 // 0 = Wih half, 1 = Whh half
        int c0 = s0 & 127;                      // float4 col within the 512-float row
        const float* rowbase = (hh ? Whh : Wih) + (size_t)(gg * DD + j) * DD;
        glds16(rowbase + 4 * (c0 + lane), (float*)Wl + 4 * s0);
    }
    if (tid < 64) {
        rows_s[tid]  = xrow ? xrow[tid] : tid;
        prows_s[tid] = prow[tid];
    }
    __syncthreads();    // rows_s visible (also drains W burst)

    // stage chunk ch into U[buf]: 64 rows x 64 floats; wave w stages rows i*4+w
    auto stage = [&](int ch, int buf) {
        int k0 = ch * 64;
        #pragma unroll
        for (int i = 0; i < 16; i++) {
            int bb = i * 4 + w;                 // wave-uniform row
            const float* src;
            if (k0 < 512) src = xbase + (size_t)rows_s[bb] * DD + k0 + lane;
            else          src = hsrc + (size_t)prows_s[bb] * DD + (k0 - 512) + lane;
            glds4(src, &U[buf][bb][0]);
        }
    };

    stage(0, 0);
    __syncthreads();    // drain stage 0

    double a0 = 0.0, a1 = 0.0, a2 = 0.0, a3 = 0.0;   // ILP-4 chains (global k%4)
    for (int ch = 0; ch < 16; ch++) {
        int cur = ch & 1;
        if (ch < 15) stage(ch + 1, cur ^ 1);    // issue next-chunk loads (other buffer)
        const float* Wrow = &Wl[g][ch * 64];    // wave-uniform broadcast reads
        #pragma unroll 8
        for (int kk = 0; kk < 64; kk += 4) {
            a0 = fma((double)U[cur][b][kk + 0], (double)Wrow[kk + 0], a0);
            a1 = fma((double)U[cur][b][kk + 1], (double)Wrow[kk + 1], a1);
            a2 = fma((double)U[cur][b][kk + 2], (double)Wrow[kk + 2], a2);
            a3 = fma((double)U[cur][b][kk + 3], (double)Wrow[kk + 3], a3);
        }
        __syncthreads();    // drains next-chunk loads; frees cur buffer for ch+2
    }
    Z[g][b] = ((a0 + a1) + (a2 + a3));
    __syncthreads();

    if (tid < 64) {
        double zi = Z[0][b] + (double)bias[0 * DD + j];
        double zf = Z[1][b] + (double)bias[1 * DD + j];
        double zg = Z[2][b] + (double)bias[2 * DD + j];
        double zo = Z[3][b] + (double)bias[3 * DD + j];
        double si = 1.0 / (1.0 + exp(-zi));
        double sf = 1.0 / (1.0 + exp(-zf));
        double so = 1.0 / (1.0 + exp(-zo));
        double cold = (double)csrc[(size_t)prows_s[b] * DD + j];
        double cn = sf * cold + si * tanh(zg);
        double hn = so * tanh(cn);
        hdst[b * DD + j] = (float)hn;   // fp32 boundary
        cdst[b * DD + j] = (float)cn;
    }
}

// ---------------------------------------------------------------- projection GEMM, full K, 2-phase dbuf
// grid NVT=500 blocks, 256 threads, thread tile 4b x 4v, fp64 acc over K=512,
// writes fp32 logits (+bias) directly. FMA order bitwise-identical to R13.
__global__ __launch_bounds__(256) void proj_kernel(
    const float* __restrict__ h1, const float* __restrict__ Wp,
    const float* __restrict__ bp, float* __restrict__ outf)
{
    __shared__ float sh[2][64][68];    // [buf][b][k-chunk]
    __shared__ float sw[2][64][68];    // [buf][k-chunk][v]
    int vbase = blockIdx.x * VT;
    int tid = threadIdx.x;
    int lane = tid & 63;
    int w = tid >> 6;
    int b0 = (tid >> 4) * 4;
    int v0 = (tid & 15) * 4;

    auto stage = [&](int ch, int buf) {
        int k0 = ch * 64;
        #pragma unroll
        for (int i = 0; i < 16; i++) {          // sh: row bb = i*4+w
            int bb = i * 4 + w;
            glds4(h1 + (size_t)bb * DD + k0 + lane, &sh[buf][bb][0]);
        }
        #pragma unroll
        for (int i = 0; i < 16; i++) {          // sw: row kk = i*4+w
            int kk = i * 4 + w;
            glds4(Wp + (size_t)(k0 + kk) * VV + vbase + lane, &sw[buf][kk][0]);
        }
    };

    double acc[4][4];
    #pragma unroll
    for (int i = 0; i < 4; i++)
        #pragma unroll
        for (int q = 0; q < 4; q++) acc[i][q] = 0.0;

    stage(0, 0);
    __syncthreads();    // drain stage 0

    for (int ch = 0; ch < 8; ch++) {
        int cur = ch & 1;
        if (ch < 7) stage(ch + 1, cur ^ 1);     // issue next-chunk loads
        #pragma unroll
        for (int k4 = 0; k4 < 16; k4++) {
            int k = k4 * 4;
            float4 h4[4], w4[4];
            #pragma unroll
            for (int i = 0; i < 4; i++) h4[i] = *(const float4*)&sh[cur][b0 + i][k];
            #pragma unroll
            for (int kk = 0; kk < 4; kk++) w4[kk] = *(const float4*)&sw[cur][k + kk][v0];
            #pragma unroll
            for (int i = 0; i < 4; i++) {
                const float hh[4] = {h4[i].x, h4[i].y, h4[i].z, h4[i].w};
                #pragma unroll
                for (int kk = 0; kk < 4; kk++) {
                    double hd = (double)hh[kk];
                    const float ww[4] = {w4[kk].x, w4[kk].y, w4[kk].z, w4[kk].w};
                    #pragma unroll
                    for (int q = 0; q < 4; q++)
                        acc[i][q] = fma(hd, (double)ww[q], acc[i][q]);
                }
            }
        }
        __syncthreads();    // drains next-chunk loads; frees cur buffer
    }

    #pragma unroll
    for (int i = 0; i < 4; i++) {
        int brow = b0 + i;
        #pragma unroll
        for (int q = 0; q < 4; q++) {
            int v = vbase + v0 + q;
            outf[(size_t)brow * VV + v] = (float)(acc[i][q] + (double)bp[v]);  // fp32 boundary
        }
    }
}

// ---------------------------------------------------------------- fused LSE + row top-4 (fp32 logits in)
#define NPT 32   // ceil(32000/1024)
__global__ __launch_bounds__(1024) void row_kernel(
    const float* __restrict__ outf, const float* __restrict__ lp,
    const int* __restrict__ fin,
    float* __restrict__ rcv, int* __restrict__ rci, int step0)
{
    int row = blockIdx.x;
    int j   = row & 3;
    int tid = threadIdx.x;
    int base_idx = j * VV;

    float lp_r = step0 ? 0.0f : lp[row];
    int   f    = step0 ? 0    : fin[row];
    if (step0 && j != 0) {
        if (tid < 4) { rcv[row * 4 + tid] = NEGF; rci[row * 4 + tid] = base_idx + tid; }
        return;
    }
    if (f) {
        if (tid < 4) {
            rcv[row * 4 + tid] = (tid == 0) ? lp_r : NEGF;
            rci[row * 4 + tid] = base_idx + tid;
        }
        return;
    }

    const float* xo = outf + (size_t)row * VV;
    __shared__ double red[1024];

    // ---- pass 1: load fp32 logits, cache in regs, max
    float zreg[NPT];
    double m = -1e300;
    #pragma unroll
    for (int q = 0; q < NPT; q++) {
        int i = tid + q * 1024;
        float zf = 0.0f;
        if (i < VV) {
            zf = xo[i];
            m = fmax(m, (double)zf);
        }
        zreg[q] = zf;
    }

    red[tid] = m; __syncthreads();
    for (int s = 512; s > 0; s >>= 1) {
        if (tid < s) red[tid] = fmax(red[tid], red[tid + s]);
        __syncthreads();
    }
    m = red[0];
    __syncthreads();

    // ---- pass 2: sumexp from registers
    double sum = 0.0;
    #pragma unroll
    for (int q = 0; q < NPT; q++) {
        int i = tid + q * 1024;
        if (i < VV) sum += exp((double)zreg[q] - m);
    }
    red[tid] = sum; __syncthreads();
    for (int s = 512; s > 0; s >>= 1) {
        if (tid < s) red[tid] += red[tid + s];
        __syncthreads();
    }
    double lse = m + log(red[0]);
    __syncthreads();

    // ---- pass 3: per-thread top-4 from registers
    float bv[4]; int bx[4];
    #pragma unroll
    for (int q = 0; q < 4; q++) { bv[q] = -3.4e38f; bx[q] = 0x7fffffff; }
    #pragma unroll
    for (int q = 0; q < NPT; q++) {
        int i = tid + q * 1024;
        if (i < VV) {
            float lgp32 = (float)((double)zreg[q] - lse);
            float val   = (float)((double)lp_r + (double)lgp32);
            int idx = base_idx + i;
            if (better(val, idx, bv[3], bx[3])) {
                bv[3] = val; bx[3] = idx;
                #pragma unroll
                for (int s = 3; s > 0; s--) {
                    if (better(bv[s], bx[s], bv[s - 1], bx[s - 1])) {
                        float tv2 = bv[s]; bv[s] = bv[s - 1]; bv[s - 1] = tv2;
                        int ti2 = bx[s]; bx[s] = bx[s - 1]; bx[s - 1] = ti2;
                    }
                }
            }
        }
    }

    __shared__ float sv[1024][4];
    __shared__ int   si_[1024][4];
    #pragma unroll
    for (int q = 0; q < 4; q++) { sv[tid][q] = bv[q]; si_[tid][q] = bx[q]; }
    __syncthreads();
    for (int s = 512; s > 0; s >>= 1) {
        if (tid < s) {
            float av[4], ov[4], mv[4]; int ai[4], oi[4], mi[4];
            #pragma unroll
            for (int q = 0; q < 4; q++) {
                av[q] = sv[tid][q];     ai[q] = si_[tid][q];
                ov[q] = sv[tid + s][q]; oi[q] = si_[tid + s][q];
            }
            int pa = 0, pb = 0;
            #pragma unroll
            for (int q = 0; q < 4; q++) {
                bool takeA = (pb >= 4) || (pa < 4 && better(av[pa], ai[pa], ov[pb], oi[pb]));
                if (takeA) { mv[q] = av[pa]; mi[q] = ai[pa]; pa++; }
                else       { mv[q] = ov[pb]; mi[q] = oi[pb]; pb++; }
            }
            #pragma unroll
            for (int q = 0; q < 4; q++) { sv[tid][q] = mv[q]; si_[tid][q] = mi[q]; }
        }
        __syncthreads();
    }
    if (tid < 4) {
        rcv[row * 4 + tid] = sv[0][tid];
        rci[row * 4 + tid] = si_[0][tid];
    }
}

// ---------------------------------------------------------------- merge 16 candidates/batch + state update
__global__ void merge_update_kernel(
    const float* __restrict__ rcv, const int* __restrict__ rci,
    float* __restrict__ lp, int* __restrict__ fin,
    int* __restrict__ tokens, int* __restrict__ pidx,
    int* __restrict__ bo, int t)
{
    int b = threadIdx.x;           // 64
    int bi = b >> 2, r = b & 3;

    float cv[16]; int ci[16];
    #pragma unroll
    for (int c = 0; c < 16; c++) { cv[c] = rcv[bi * 16 + c]; ci[c] = rci[bi * 16 + c]; }

    int sel = 0;
    #pragma unroll
    for (int c = 0; c < 16; c++) {
        int rank = 0;
        #pragma unroll
        for (int d = 0; d < 16; d++)
            if (d != c && better(cv[d], ci[d], cv[c], ci[c])) rank++;
        if (rank == r) sel = c;
    }

    float v = cv[sel];
    int flat = ci[sel];
    int q = flat / VV;
    int p = q + bi * 4;
    int tok = flat - q * VV;
    int oldfin = fin[p];
    int col[TSTEPS + 1];
    #pragma unroll
    for (int rr = 0; rr <= TSTEPS; rr++) col[rr] = bo[rr * BB + p];
    __syncthreads();
    #pragma unroll
    for (int rr = 0; rr <= TSTEPS; rr++) bo[rr * BB + b] = col[rr];
    bo[(t + 1) * BB + b] = tok;
    fin[b]    = oldfin | (tok == EOSTOK);
    lp[b]     = v;
    tokens[b] = tok;
    pidx[b]   = p;
}

// ---------------------------------------------------------------- final beam_out -> float
__global__ void final_kernel(const int* __restrict__ bo, float* __restrict__ out)
{
    int i = blockIdx.x * blockDim.x + threadIdx.x;
    if (i < (TSTEPS + 1) * BB) out[i] = (float)bo[i];
}

// ---------------------------------------------------------------- host
extern "C" void kernel_launch(void* const* d_in, const int* in_sizes, int n_in,
                              void* d_out, int out_size, void* d_ws, size_t ws_size,
                              hipStream_t stream)
{
    const int*   inputs = (const int*)d_in[0];
    const float* h0   = (const float*)d_in[1];
    const float* c0   = (const float*)d_in[2];
    const float* emb  = (const float*)d_in[3];
    const float* Wih0 = (const float*)d_in[4];
    const float* Whh0 = (const float*)d_in[5];
    const float* b0   = (const float*)d_in[6];
    const float* Wih1 = (const float*)d_in[7];
    const float* Whh1 = (const float*)d_in[8];
    const float* b1   = (const float*)d_in[9];
    const float* Wp   = (const float*)d_in[10];
    const float* bp   = (const float*)d_in[11];
    float* out = (float*)d_out;

    char* w = (char*)d_ws;
    size_t off = 0;
    auto alloc = [&](size_t bytes) { void* p = w + off; off += (bytes + 255) & ~255ULL; return p; };
    float* h0s[2], *c0s[2], *h1s[2], *c1s[2];
    for (int s = 0; s < 2; s++) {
        h0s[s] = (float*)alloc(BB * DD * 4);
        c0s[s] = (float*)alloc(BB * DD * 4);
        h1s[s] = (float*)alloc(BB * DD * 4);
        c1s[s] = (float*)alloc(BB * DD * 4);
    }
    float* rcv   = (float*)alloc(BB * 4 * 4);
    int*   rci   = (int*)alloc(BB * 4 * 4);
    float* lp    = (float*)alloc(BB * 4);
    int* pidx    = (int*)alloc(BB * 4);
    int* tokens  = (int*)alloc(BB * 4);
    int* fin     = (int*)alloc(BB * 4);
    int* bo      = (int*)alloc((TSTEPS + 1) * BB * 4);

    init_kernel<<<128, 256, 0, stream>>>(inputs, h0, c0,
                                         h0s[0], c0s[0], h1s[0], c1s[0],
                                         tokens, pidx, fin, lp, bo);

    for (int t = 0; t < TSTEPS; t++) {
        int s = t & 1, d2 = s ^ 1;
        lstm_kernel<<<512, 256, 0, stream>>>(emb, tokens, h0s[s], c0s[s], pidx,
                                             h0s[d2], c0s[d2], Wih0, Whh0, b0);
        lstm_kernel<<<512, 256, 0, stream>>>(h0s[d2], nullptr, h1s[s], c1s[s], pidx,
                                             h1s[d2], c1s[d2], Wih1, Whh1, b1);

        float* outf = out + (size_t)t * BB * VV;
        proj_kernel<<<NVT, 256, 0, stream>>>(h1s[d2], Wp, bp, outf);
        row_kernel<<<BB, 1024, 0, stream>>>(outf, lp, fin, rcv, rci, t == 0 ? 1 : 0);
        merge_update_kernel<<<1, 64, 0, stream>>>(rcv, rci, lp, fin, tokens, pidx, bo, t);
    }
    final_kernel<<<5, 256, 0, stream>>>(bo, out + (size_t)TSTEPS * BB * VV);
}

// Round 16
// 2854.529 us; speedup vs baseline: 1.0216x; 1.0216x over previous
//
#include <hip/hip_runtime.h>
#include <math.h>

#define BS     16
#define NB     4
#define BB     64      // BS*NB
#define DD     512
#define VV     32000
#define TSTEPS 16
#define EOSTOK 2
#define NEGF   (-1e32f)
#define VT2    32
#define NVT2   (VV / VT2)   // 1000

__device__ __forceinline__ bool better(float av, int ai, float bv, int bi_) {
    return (av > bv) || (av == bv && ai < bi_);
}

// async global->LDS staging, no VGPR round-trip (gfx950)
__device__ __forceinline__ void glds4(const float* src, float* dst) {
    __builtin_amdgcn_global_load_lds((const __attribute__((address_space(1))) void*)src,
                                     (__attribute__((address_space(3))) void*)dst, 4, 0, 0);
}
__device__ __forceinline__ void glds16(const float* src, float* dst) {
    __builtin_amdgcn_global_load_lds((const __attribute__((address_space(1))) void*)src,
                                     (__attribute__((address_space(3))) void*)dst, 16, 0, 0);
}

// ---------------------------------------------------------------- init (fp32 states)
__global__ void init_kernel(const int* __restrict__ inputs,
                            const float* __restrict__ h0, const float* __restrict__ c0,
                            float* __restrict__ h0s, float* __restrict__ c0s,
                            float* __restrict__ h1s, float* __restrict__ c1s,
                            int* __restrict__ tokens, int* __restrict__ pidx,
                            int* __restrict__ fin, float* __restrict__ lp,
                            int* __restrict__ bo)
{
    int tid = blockIdx.x * blockDim.x + threadIdx.x;
    int total = BB * DD;
    for (int i = tid; i < total; i += gridDim.x * blockDim.x) {
        int b = i / DD;
        int d = i % DD;
        int src0 = 0 * BS * DD + (b >> 2) * DD + d;
        int src1 = 1 * BS * DD + (b >> 2) * DD + d;
        h0s[i] = h0[src0];
        c0s[i] = c0[src0];
        h1s[i] = h0[src1];
        c1s[i] = c0[src1];
    }
    if (tid < BB) {
        tokens[tid] = inputs[tid >> 2];
        pidx[tid]   = tid;
        fin[tid]    = 0;
        lp[tid]     = 0.0f;
        bo[0 * BB + tid] = inputs[tid >> 2];
        for (int r = 1; r <= TSTEPS; r++) bo[r * BB + tid] = 0;
    }
}

// ---------------------------------------------------------------- LSTM: beam-split blocks
// 1024 blocks x 128 threads; block = (j = bid>>1, beam-half = bid&1).
// Per-thread (beam, gate) FMA chain (global k%4, ascending k) bitwise-identical to R13.
__global__ __launch_bounds__(128) void lstm_kernel(
    const float* __restrict__ xbase, const int* __restrict__ xrow,
    const float* __restrict__ hsrc,  const float* __restrict__ csrc,
    const int* __restrict__ prow,
    float* __restrict__ hdst, float* __restrict__ cdst,
    const float* __restrict__ Wih, const float* __restrict__ Whh,
    const float* __restrict__ bias)
{
    __shared__ float U[32][129];    // [local beam][k]: bank (b+k)%32, 2-way max
    __shared__ float Wl[4][1024];   // all weight rows for this j (16 KB)
    __shared__ double Z[4][32];
    __shared__ int rows_s[32], prows_s[32];
    int tid = threadIdx.x;
    int j  = blockIdx.x >> 1;
    int bo_ = (blockIdx.x & 1) * 32;   // beam-half base
    int b = tid & 31;                  // local beam
    int g = tid >> 5;                  // gate 0..3
    int lane = tid & 63;
    int w = tid >> 6;                  // wave id 0..1

    // ---- W burst: 16 KB via width-16 async copies, 2 waves x 8 instrs
    #pragma unroll
    for (int i = 0; i < 8; i++) {
        int s0 = (i * 2 + w) * 64;              // wave-uniform float4 slot base 0..960
        int gg = s0 >> 8;                       // gate
        int hh = (s0 >> 7) & 1;                 // 0 = Wih half, 1 = Whh half
        int c0 = s0 & 127;                      // float4 col within 512-float row
        const float* rowbase = (hh ? Whh : Wih) + (size_t)(gg * DD + j) * DD;
        glds16(rowbase + 4 * (c0 + lane), (float*)Wl + 4 * s0);
    }
    if (tid < 32) {
        rows_s[tid]  = xrow ? xrow[bo_ + tid] : (bo_ + tid);
        prows_s[tid] = prow[bo_ + tid];
    }

    double a0 = 0.0, a1 = 0.0, a2 = 0.0, a3 = 0.0;   // ILP-4 chains (global k%4)
    for (int ch = 0; ch < 8; ch++) {
        int k0 = ch * 128;
        __syncthreads();    // rows_s visible / prev readers done; drains outstanding glds
        #pragma unroll
        for (int i = 0; i < 32; i++) {          // U stage: 32 rows x 2 half-row spans
            int s = i * 2 + w;                  // span 0..63, wave-uniform per instr
            int bb = s >> 1;
            int kk0 = (s & 1) * 64;
            const float* src;
            if (k0 < 512) src = xbase + (size_t)rows_s[bb] * DD + k0 + kk0 + lane;
            else          src = hsrc + (size_t)prows_s[bb] * DD + (k0 - 512) + kk0 + lane;
            glds4(src, &U[bb][kk0]);
        }
        __syncthreads();    // vmcnt drained -> LDS writes landed
        const float* Wrow = &Wl[g][k0];
        #pragma unroll 8
        for (int kk = 0; kk < 128; kk += 4) {
            a0 = fma((double)U[b][kk + 0], (double)Wrow[kk + 0], a0);
            a1 = fma((double)U[b][kk + 1], (double)Wrow[kk + 1], a1);
            a2 = fma((double)U[b][kk + 2], (double)Wrow[kk + 2], a2);
            a3 = fma((double)U[b][kk + 3], (double)Wrow[kk + 3], a3);
        }
    }
    Z[g][b] = ((a0 + a1) + (a2 + a3));
    __syncthreads();

    if (tid < 32) {
        int gb = bo_ + b;   // global beam
        double zi = Z[0][b] + (double)bias[0 * DD + j];
        double zf = Z[1][b] + (double)bias[1 * DD + j];
        double zg = Z[2][b] + (double)bias[2 * DD + j];
        double zo = Z[3][b] + (double)bias[3 * DD + j];
        double si = 1.0 / (1.0 + exp(-zi));
        double sf = 1.0 / (1.0 + exp(-zf));
        double so = 1.0 / (1.0 + exp(-zo));
        double cold = (double)csrc[(size_t)prows_s[b] * DD + j];
        double cn = sf * cold + si * tanh(zg);
        double hn = so * tanh(cn);
        hdst[gb * DD + j] = (float)hn;   // fp32 boundary
        cdst[gb * DD + j] = (float)cn;
    }
}

// ---------------------------------------------------------------- projection GEMM, full K, VT=32
// grid 1000 blocks (4/CU), 256 threads, thread tile 4b x 2v, fp64 acc over K=512,
// writes fp32 logits (+bias) directly. Per-logit FMA order bitwise-identical to R13.
__global__ __launch_bounds__(256) void proj_kernel(
    const float* __restrict__ h1, const float* __restrict__ Wp,
    const float* __restrict__ bp, float* __restrict__ outf)
{
    __shared__ float sh[64][68];    // [b][k-chunk], padded
    __shared__ float sw[64][32];    // [k-chunk][v], unpadded (paired-row 256B wave-writes)
    int vbase = blockIdx.x * VT2;
    int tid = threadIdx.x;
    int lane = tid & 63;
    int w = tid >> 6;
    int b0 = (tid >> 4) * 4;
    int v0 = (tid & 15) * 2;

    double acc[4][2];
    #pragma unroll
    for (int i = 0; i < 4; i++) { acc[i][0] = 0.0; acc[i][1] = 0.0; }

    for (int ch = 0; ch < 8; ch++) {
        int k0 = ch * 64;
        __syncthreads();
        #pragma unroll
        for (int i = 0; i < 16; i++) {          // sh: row bb = i*4+w, cols 0..63
            int bb = i * 4 + w;
            glds4(h1 + (size_t)bb * DD + k0 + lane, &sh[bb][0]);
        }
        #pragma unroll
        for (int i = 0; i < 8; i++) {           // sw: row pair 2r2,2r2+1 per 256B wave-write
            int r2 = i * 4 + w;                 // 0..31, wave-uniform per instr
            const float* src = Wp + (size_t)(k0 + 2 * r2 + (lane >> 5)) * VV
                                  + vbase + (lane & 31);
            glds4(src, &sw[2 * r2][0]);
        }
        __syncthreads();
        #pragma unroll
        for (int k4 = 0; k4 < 16; k4++) {
            int k = k4 * 4;
            float4 h4[4]; float2 w2[4];
            #pragma unroll
            for (int i = 0; i < 4; i++) h4[i] = *(const float4*)&sh[b0 + i][k];
            #pragma unroll
            for (int kk = 0; kk < 4; kk++) w2[kk] = *(const float2*)&sw[k + kk][v0];
            #pragma unroll
            for (int i = 0; i < 4; i++) {
                const float hh[4] = {h4[i].x, h4[i].y, h4[i].z, h4[i].w};
                #pragma unroll
                for (int kk = 0; kk < 4; kk++) {
                    double hd = (double)hh[kk];
                    acc[i][0] = fma(hd, (double)w2[kk].x, acc[i][0]);
                    acc[i][1] = fma(hd, (double)w2[kk].y, acc[i][1]);
                }
            }
        }
    }

    #pragma unroll
    for (int i = 0; i < 4; i++) {
        int brow = b0 + i;
        #pragma unroll
        for (int q = 0; q < 2; q++) {
            int v = vbase + v0 + q;
            outf[(size_t)brow * VV + v] = (float)(acc[i][q] + (double)bp[v]);  // fp32 boundary
        }
    }
}

// ---------------------------------------------------------------- fused LSE + row top-4 (fp32 logits in)
#define NPT 32   // ceil(32000/1024)
__global__ __launch_bounds__(1024) void row_kernel(
    const float* __restrict__ outf, const float* __restrict__ lp,
    const int* __restrict__ fin,
    float* __restrict__ rcv, int* __restrict__ rci, int step0)
{
    int row = blockIdx.x;
    int j   = row & 3;
    int tid = threadIdx.x;
    int base_idx = j * VV;

    float lp_r = step0 ? 0.0f : lp[row];
    int   f    = step0 ? 0    : fin[row];
    if (step0 && j != 0) {
        if (tid < 4) { rcv[row * 4 + tid] = NEGF; rci[row * 4 + tid] = base_idx + tid; }
        return;
    }
    if (f) {
        if (tid < 4) {
            rcv[row * 4 + tid] = (tid == 0) ? lp_r : NEGF;
            rci[row * 4 + tid] = base_idx + tid;
        }
        return;
    }

    const float* xo = outf + (size_t)row * VV;
    __shared__ double red[1024];

    // ---- pass 1: load fp32 logits, cache in regs, max
    float zreg[NPT];
    double m = -1e300;
    #pragma unroll
    for (int q = 0; q < NPT; q++) {
        int i = tid + q * 1024;
        float zf = 0.0f;
        if (i < VV) {
            zf = xo[i];
            m = fmax(m, (double)zf);
        }
        zreg[q] = zf;
    }

    red[tid] = m; __syncthreads();
    for (int s = 512; s > 0; s >>= 1) {
        if (tid < s) red[tid] = fmax(red[tid], red[tid + s]);
        __syncthreads();
    }
    m = red[0];
    __syncthreads();

    // ---- pass 2: sumexp from registers
    double sum = 0.0;
    #pragma unroll
    for (int q = 0; q < NPT; q++) {
        int i = tid + q * 1024;
        if (i < VV) sum += exp((double)zreg[q] - m);
    }
    red[tid] = sum; __syncthreads();
    for (int s = 512; s > 0; s >>= 1) {
        if (tid < s) red[tid] += red[tid + s];
        __syncthreads();
    }
    double lse = m + log(red[0]);
    __syncthreads();

    // ---- pass 3: per-thread top-4 from registers
    float bv[4]; int bx[4];
    #pragma unroll
    for (int q = 0; q < 4; q++) { bv[q] = -3.4e38f; bx[q] = 0x7fffffff; }
    #pragma unroll
    for (int q = 0; q < NPT; q++) {
        int i = tid + q * 1024;
        if (i < VV) {
            float lgp32 = (float)((double)zreg[q] - lse);
            float val   = (float)((double)lp_r + (double)lgp32);
            int idx = base_idx + i;
            if (better(val, idx, bv[3], bx[3])) {
                bv[3] = val; bx[3] = idx;
                #pragma unroll
                for (int s = 3; s > 0; s--) {
                    if (better(bv[s], bx[s], bv[s - 1], bx[s - 1])) {
                        float tv2 = bv[s]; bv[s] = bv[s - 1]; bv[s - 1] = tv2;
                        int ti2 = bx[s]; bx[s] = bx[s - 1]; bx[s - 1] = ti2;
                    }
                }
            }
        }
    }

    __shared__ float sv[1024][4];
    __shared__ int   si_[1024][4];
    #pragma unroll
    for (int q = 0; q < 4; q++) { sv[tid][q] = bv[q]; si_[tid][q] = bx[q]; }
    __syncthreads();
    for (int s = 512; s > 0; s >>= 1) {
        if (tid < s) {
            float av[4], ov[4], mv[4]; int ai[4], oi[4], mi[4];
            #pragma unroll
            for (int q = 0; q < 4; q++) {
                av[q] = sv[tid][q];     ai[q] = si_[tid][q];
                ov[q] = sv[tid + s][q]; oi[q] = si_[tid + s][q];
            }
            int pa = 0, pb = 0;
            #pragma unroll
            for (int q = 0; q < 4; q++) {
                bool takeA = (pb >= 4) || (pa < 4 && better(av[pa], ai[pa], ov[pb], oi[pb]));
                if (takeA) { mv[q] = av[pa]; mi[q] = ai[pa]; pa++; }
                else       { mv[q] = ov[pb]; mi[q] = oi[pb]; pb++; }
            }
            #pragma unroll
            for (int q = 0; q < 4; q++) { sv[tid][q] = mv[q]; si_[tid][q] = mi[q]; }
        }
        __syncthreads();
    }
    if (tid < 4) {
        rcv[row * 4 + tid] = sv[0][tid];
        rci[row * 4 + tid] = si_[0][tid];
    }
}

// ---------------------------------------------------------------- merge 16 candidates/batch + state update
__global__ void merge_update_kernel(
    const float* __restrict__ rcv, const int* __restrict__ rci,
    float* __restrict__ lp, int* __restrict__ fin,
    int* __restrict__ tokens, int* __restrict__ pidx,
    int* __restrict__ bo, int t)
{
    int b = threadIdx.x;           // 64
    int bi = b >> 2, r = b & 3;

    float cv[16]; int ci[16];
    #pragma unroll
    for (int c = 0; c < 16; c++) { cv[c] = rcv[bi * 16 + c]; ci[c] = rci[bi * 16 + c]; }

    int sel = 0;
    #pragma unroll
    for (int c = 0; c < 16; c++) {
        int rank = 0;
        #pragma unroll
        for (int d = 0; d < 16; d++)
            if (d != c && better(cv[d], ci[d], cv[c], ci[c])) rank++;
        if (rank == r) sel = c;
    }

    float v = cv[sel];
    int flat = ci[sel];
    int q = flat / VV;
    int p = q + bi * 4;
    int tok = flat - q * VV;
    int oldfin = fin[p];
    int col[TSTEPS + 1];
    #pragma unroll
    for (int rr = 0; rr <= TSTEPS; rr++) col[rr] = bo[rr * BB + p];
    __syncthreads();
    #pragma unroll
    for (int rr = 0; rr <= TSTEPS; rr++) bo[rr * BB + b] = col[rr];
    bo[(t + 1) * BB + b] = tok;
    fin[b]    = oldfin | (tok == EOSTOK);
    lp[b]     = v;
    tokens[b] = tok;
    pidx[b]   = p;
}

// ---------------------------------------------------------------- final beam_out -> float
__global__ void final_kernel(const int* __restrict__ bo, float* __restrict__ out)
{
    int i = blockIdx.x * blockDim.x + threadIdx.x;
    if (i < (TSTEPS + 1) * BB) out[i] = (float)bo[i];
}

// ---------------------------------------------------------------- host
extern "C" void kernel_launch(void* const* d_in, const int* in_sizes, int n_in,
                              void* d_out, int out_size, void* d_ws, size_t ws_size,
                              hipStream_t stream)
{
    const int*   inputs = (const int*)d_in[0];
    const float* h0   = (const float*)d_in[1];
    const float* c0   = (const float*)d_in[2];
    const float* emb  = (const float*)d_in[3];
    const float* Wih0 = (const float*)d_in[4];
    const float* Whh0 = (const float*)d_in[5];
    const float* b0   = (const float*)d_in[6];
    const float* Wih1 = (const float*)d_in[7];
    const float* Whh1 = (const float*)d_in[8];
    const float* b1   = (const float*)d_in[9];
    const float* Wp   = (const float*)d_in[10];
    const float* bp   = (const float*)d_in[11];
    float* out = (float*)d_out;

    char* w = (char*)d_ws;
    size_t off = 0;
    auto alloc = [&](size_t bytes) { void* p = w + off; off += (bytes + 255) & ~255ULL; return p; };
    float* h0s[2], *c0s[2], *h1s[2], *c1s[2];
    for (int s = 0; s < 2; s++) {
        h0s[s] = (float*)alloc(BB * DD * 4);
        c0s[s] = (float*)alloc(BB * DD * 4);
        h1s[s] = (float*)alloc(BB * DD * 4);
        c1s[s] = (float*)alloc(BB * DD * 4);
    }
    float* rcv   = (float*)alloc(BB * 4 * 4);
    int*   rci   = (int*)alloc(BB * 4 * 4);
    float* lp    = (float*)alloc(BB * 4);
    int* pidx    = (int*)alloc(BB * 4);
    int* tokens  = (int*)alloc(BB * 4);
    int* fin     = (int*)alloc(BB * 4);
    int* bo      = (int*)alloc((TSTEPS + 1) * BB * 4);

    init_kernel<<<128, 256, 0, stream>>>(inputs, h0, c0,
                                         h0s[0], c0s[0], h1s[0], c1s[0],
                                         tokens, pidx, fin, lp, bo);

    for (int t = 0; t < TSTEPS; t++) {
        int s = t & 1, d2 = s ^ 1;
        lstm_kernel<<<1024, 128, 0, stream>>>(emb, tokens, h0s[s], c0s[s], pidx,
                                              h0s[d2], c0s[d2], Wih0, Whh0, b0);
        lstm_kernel<<<1024, 128, 0, stream>>>(h0s[d2], nullptr, h1s[s], c1s[s], pidx,
                                              h1s[d2], c1s[d2], Wih1, Whh1, b1);

        float* outf = out + (size_t)t * BB * VV;
        proj_kernel<<<NVT2, 256, 0, stream>>>(h1s[d2], Wp, bp, outf);
        row_kernel<<<BB, 1024, 0, stream>>>(outf, lp, fin, rcv, rci, t == 0 ? 1 : 0);
        merge_update_kernel<<<1, 64, 0, stream>>>(rcv, rci, lp, fin, tokens, pidx, bo, t);
    }
    final_kernel<<<5, 256, 0, stream>>>(bo, out + (size_t)TSTEPS * BB * VV);
}

// Round 17
// 2707.788 us; speedup vs baseline: 1.0770x; 1.0542x over previous
//
#include <hip/hip_runtime.h>
#include <math.h>

#define BS     16
#define NB     4
#define BB     64      // BS*NB
#define DD     512
#define VV     32000
#define TSTEPS 16
#define EOSTOK 2
#define NEGF   (-1e32f)
#define VT     64
#define NVT    (VV / VT)   // 500

__device__ __forceinline__ bool better(float av, int ai, float bv, int bi_) {
    return (av > bv) || (av == bv && ai < bi_);
}

// async global->LDS staging, no VGPR round-trip (gfx950)
__device__ __forceinline__ void glds4(const float* src, float* dst) {
    __builtin_amdgcn_global_load_lds((const __attribute__((address_space(1))) void*)src,
                                     (__attribute__((address_space(3))) void*)dst, 4, 0, 0);
}
__device__ __forceinline__ void glds16(const float* src, float* dst) {
    __builtin_amdgcn_global_load_lds((const __attribute__((address_space(1))) void*)src,
                                     (__attribute__((address_space(3))) void*)dst, 16, 0, 0);
}

// ---------------------------------------------------------------- init (fp32 states)
__global__ void init_kernel(const int* __restrict__ inputs,
                            const float* __restrict__ h0, const float* __restrict__ c0,
                            float* __restrict__ h0s, float* __restrict__ c0s,
                            float* __restrict__ h1s, float* __restrict__ c1s,
                            int* __restrict__ tokens, int* __restrict__ pidx,
                            int* __restrict__ fin, float* __restrict__ lp,
                            int* __restrict__ bo, unsigned int* __restrict__ counter)
{
    int tid = blockIdx.x * blockDim.x + threadIdx.x;
    int total = BB * DD;
    for (int i = tid; i < total; i += gridDim.x * blockDim.x) {
        int b = i / DD;
        int d = i % DD;
        int src0 = 0 * BS * DD + (b >> 2) * DD + d;
        int src1 = 1 * BS * DD + (b >> 2) * DD + d;
        h0s[i] = h0[src0];
        c0s[i] = c0[src0];
        h1s[i] = h0[src1];
        c1s[i] = c0[src1];
    }
    if (tid == 0) *counter = 0u;
    if (tid < BB) {
        tokens[tid] = inputs[tid >> 2];
        pidx[tid]   = tid;
        fin[tid]    = 0;
        lp[tid]     = 0.0f;
        bo[0 * BB + tid] = inputs[tid >> 2];
        for (int r = 1; r <= TSTEPS; r++) bo[r * BB + tid] = 0;
    }
}

// ---------------------------------------------------------------- LSTM: beam-split blocks (R16 form)
// 1024 blocks x 128 threads; block = (j = bid>>1, beam-half = bid&1).
__global__ __launch_bounds__(128) void lstm_kernel(
    const float* __restrict__ xbase, const int* __restrict__ xrow,
    const float* __restrict__ hsrc,  const float* __restrict__ csrc,
    const int* __restrict__ prow,
    float* __restrict__ hdst, float* __restrict__ cdst,
    const float* __restrict__ Wih, const float* __restrict__ Whh,
    const float* __restrict__ bias)
{
    __shared__ float U[32][129];
    __shared__ float Wl[4][1024];
    __shared__ double Z[4][32];
    __shared__ int rows_s[32], prows_s[32];
    int tid = threadIdx.x;
    int j  = blockIdx.x >> 1;
    int bo_ = (blockIdx.x & 1) * 32;
    int b = tid & 31;
    int g = tid >> 5;
    int lane = tid & 63;
    int w = tid >> 6;

    #pragma unroll
    for (int i = 0; i < 8; i++) {
        int s0 = (i * 2 + w) * 64;
        int gg = s0 >> 8;
        int hh = (s0 >> 7) & 1;
        int c0 = s0 & 127;
        const float* rowbase = (hh ? Whh : Wih) + (size_t)(gg * DD + j) * DD;
        glds16(rowbase + 4 * (c0 + lane), (float*)Wl + 4 * s0);
    }
    if (tid < 32) {
        rows_s[tid]  = xrow ? xrow[bo_ + tid] : (bo_ + tid);
        prows_s[tid] = prow[bo_ + tid];
    }

    double a0 = 0.0, a1 = 0.0, a2 = 0.0, a3 = 0.0;
    for (int ch = 0; ch < 8; ch++) {
        int k0 = ch * 128;
        __syncthreads();
        #pragma unroll
        for (int i = 0; i < 32; i++) {
            int s = i * 2 + w;
            int bb = s >> 1;
            int kk0 = (s & 1) * 64;
            const float* src;
            if (k0 < 512) src = xbase + (size_t)rows_s[bb] * DD + k0 + kk0 + lane;
            else          src = hsrc + (size_t)prows_s[bb] * DD + (k0 - 512) + kk0 + lane;
            glds4(src, &U[bb][kk0]);
        }
        __syncthreads();
        const float* Wrow = &Wl[g][k0];
        #pragma unroll 8
        for (int kk = 0; kk < 128; kk += 4) {
            a0 = fma((double)U[b][kk + 0], (double)Wrow[kk + 0], a0);
            a1 = fma((double)U[b][kk + 1], (double)Wrow[kk + 1], a1);
            a2 = fma((double)U[b][kk + 2], (double)Wrow[kk + 2], a2);
            a3 = fma((double)U[b][kk + 3], (double)Wrow[kk + 3], a3);
        }
    }
    Z[g][b] = ((a0 + a1) + (a2 + a3));
    __syncthreads();

    if (tid < 32) {
        int gb = bo_ + b;
        double zi = Z[0][b] + (double)bias[0 * DD + j];
        double zf = Z[1][b] + (double)bias[1 * DD + j];
        double zg = Z[2][b] + (double)bias[2 * DD + j];
        double zo = Z[3][b] + (double)bias[3 * DD + j];
        double si = 1.0 / (1.0 + exp(-zi));
        double sf = 1.0 / (1.0 + exp(-zf));
        double so = 1.0 / (1.0 + exp(-zo));
        double cold = (double)csrc[(size_t)prows_s[b] * DD + j];
        double cn = sf * cold + si * tanh(zg);
        double hn = so * tanh(cn);
        hdst[gb * DD + j] = (float)hn;   // fp32 boundary
        cdst[gb * DD + j] = (float)cn;
    }
}

// ---------------------------------------------------------------- projection GEMM, full K (R13 form)
__global__ __launch_bounds__(256) void proj_kernel(
    const float* __restrict__ h1, const float* __restrict__ Wp,
    const float* __restrict__ bp, float* __restrict__ outf)
{
    __shared__ float sh[64][68];    // [b][k-chunk]
    __shared__ float sw[64][68];    // [k-chunk][v]
    int vbase = blockIdx.x * VT;
    int tid = threadIdx.x;
    int lane = tid & 63;
    int w = tid >> 6;
    int b0 = (tid >> 4) * 4;
    int v0 = (tid & 15) * 4;

    double acc[4][4];
    #pragma unroll
    for (int i = 0; i < 4; i++)
        #pragma unroll
        for (int q = 0; q < 4; q++) acc[i][q] = 0.0;

    for (int ch = 0; ch < 8; ch++) {
        int k0 = ch * 64;
        __syncthreads();
        #pragma unroll
        for (int i = 0; i < 16; i++) {
            int bb = i * 4 + w;
            glds4(h1 + (size_t)bb * DD + k0 + lane, &sh[bb][0]);
        }
        #pragma unroll
        for (int i = 0; i < 16; i++) {
            int kk = i * 4 + w;
            glds4(Wp + (size_t)(k0 + kk) * VV + vbase + lane, &sw[kk][0]);
        }
        __syncthreads();
        #pragma unroll
        for (int k4 = 0; k4 < 16; k4++) {
            int k = k4 * 4;
            float4 h4[4], w4[4];
            #pragma unroll
            for (int i = 0; i < 4; i++) h4[i] = *(const float4*)&sh[b0 + i][k];
            #pragma unroll
            for (int kk = 0; kk < 4; kk++) w4[kk] = *(const float4*)&sw[k + kk][v0];
            #pragma unroll
            for (int i = 0; i < 4; i++) {
                const float hh[4] = {h4[i].x, h4[i].y, h4[i].z, h4[i].w};
                #pragma unroll
                for (int kk = 0; kk < 4; kk++) {
                    double hd = (double)hh[kk];
                    const float ww[4] = {w4[kk].x, w4[kk].y, w4[kk].z, w4[kk].w};
                    #pragma unroll
                    for (int q = 0; q < 4; q++)
                        acc[i][q] = fma(hd, (double)ww[q], acc[i][q]);
                }
            }
        }
    }

    #pragma unroll
    for (int i = 0; i < 4; i++) {
        int brow = b0 + i;
        #pragma unroll
        for (int q = 0; q < 4; q++) {
            int v = vbase + v0 + q;
            outf[(size_t)brow * VV + v] = (float)(acc[i][q] + (double)bp[v]);  // fp32 boundary
        }
    }
}

// ---------------------------------------------------------------- fused LSE + row top-4 + last-block merge
// 64 blocks x 1024 threads. Candidates published via device-scope atomics; the
// 64th block to finish re-reads all candidates coherently (atomic RMW reads)
// and performs the beam-state merge inline. Deterministic: merge math is
// independent of which block is last.
#define NPT 32   // ceil(32000/1024)
__global__ __launch_bounds__(1024) void row_kernel(
    const float* __restrict__ outf, const float* __restrict__ lp,
    const int* __restrict__ fin,
    float* __restrict__ rcv, int* __restrict__ rci,
    int* __restrict__ tokens, int* __restrict__ pidx, int* __restrict__ bo,
    unsigned int* __restrict__ counter, int t)
{
    int step0 = (t == 0) ? 1 : 0;
    int row = blockIdx.x;
    int j   = row & 3;
    int tid = threadIdx.x;
    int base_idx = j * VV;

    __shared__ float winv[4];
    __shared__ int   win[4];
    __shared__ double red[1024];

    float lp_r = step0 ? 0.0f : lp[row];
    int   f    = step0 ? 0    : fin[row];

    bool trivial = (step0 && j != 0) || (!step0 && f);
    if (trivial) {
        if (tid < 4) {
            winv[tid] = ((!step0 && f) && tid == 0) ? lp_r : NEGF;
            win[tid]  = base_idx + tid;
        }
    } else {
        const float* xo = outf + (size_t)row * VV;

        // ---- pass 1: load fp32 logits, cache in regs, max
        float zreg[NPT];
        double m = -1e300;
        #pragma unroll
        for (int q = 0; q < NPT; q++) {
            int i = tid + q * 1024;
            float zf = 0.0f;
            if (i < VV) {
                zf = xo[i];
                m = fmax(m, (double)zf);
            }
            zreg[q] = zf;
        }

        red[tid] = m; __syncthreads();
        for (int s = 512; s > 0; s >>= 1) {
            if (tid < s) red[tid] = fmax(red[tid], red[tid + s]);
            __syncthreads();
        }
        m = red[0];
        __syncthreads();

        // ---- pass 2: sumexp from registers
        double sum = 0.0;
        #pragma unroll
        for (int q = 0; q < NPT; q++) {
            int i = tid + q * 1024;
            if (i < VV) sum += exp((double)zreg[q] - m);
        }
        red[tid] = sum; __syncthreads();
        for (int s = 512; s > 0; s >>= 1) {
            if (tid < s) red[tid] += red[tid + s];
            __syncthreads();
        }
        double lse = m + log(red[0]);
        __syncthreads();

        // ---- pass 3: per-thread top-4 from registers
        float bv[4]; int bx[4];
        #pragma unroll
        for (int q = 0; q < 4; q++) { bv[q] = -3.4e38f; bx[q] = 0x7fffffff; }
        #pragma unroll
        for (int q = 0; q < NPT; q++) {
            int i = tid + q * 1024;
            if (i < VV) {
                float lgp32 = (float)((double)zreg[q] - lse);
                float val   = (float)((double)lp_r + (double)lgp32);
                int idx = base_idx + i;
                if (better(val, idx, bv[3], bx[3])) {
                    bv[3] = val; bx[3] = idx;
                    #pragma unroll
                    for (int s = 3; s > 0; s--) {
                        if (better(bv[s], bx[s], bv[s - 1], bx[s - 1])) {
                            float tv2 = bv[s]; bv[s] = bv[s - 1]; bv[s - 1] = tv2;
                            int ti2 = bx[s]; bx[s] = bx[s - 1]; bx[s - 1] = ti2;
                        }
                    }
                }
            }
        }

        __shared__ float sv[1024][4];
        __shared__ int   si_[1024][4];
        #pragma unroll
        for (int q = 0; q < 4; q++) { sv[tid][q] = bv[q]; si_[tid][q] = bx[q]; }
        __syncthreads();
        for (int s = 512; s > 0; s >>= 1) {
            if (tid < s) {
                float av[4], ov[4], mv[4]; int ai[4], oi[4], mi[4];
                #pragma unroll
                for (int q = 0; q < 4; q++) {
                    av[q] = sv[tid][q];     ai[q] = si_[tid][q];
                    ov[q] = sv[tid + s][q]; oi[q] = si_[tid + s][q];
                }
                int pa = 0, pb = 0;
                #pragma unroll
                for (int q = 0; q < 4; q++) {
                    bool takeA = (pb >= 4) || (pa < 4 && better(av[pa], ai[pa], ov[pb], oi[pb]));
                    if (takeA) { mv[q] = av[pa]; mi[q] = ai[pa]; pa++; }
                    else       { mv[q] = ov[pb]; mi[q] = oi[pb]; pb++; }
                }
                #pragma unroll
                for (int q = 0; q < 4; q++) { sv[tid][q] = mv[q]; si_[tid][q] = mi[q]; }
            }
            __syncthreads();
        }
        if (tid < 4) { winv[tid] = sv[0][tid]; win[tid] = si_[0][tid]; }
    }
    __syncthreads();

    // ---- publish candidates (device-scope atomics: cross-XCD coherent)
    if (tid < 4) {
        atomicExch((unsigned int*)&rcv[row * 4 + tid], __float_as_uint(winv[tid]));
        atomicExch((unsigned int*)&rci[row * 4 + tid], (unsigned int)win[tid]);
        __threadfence();
    }
    __syncthreads();

    __shared__ int lastFlag;
    if (tid == 0) {
        unsigned int prev = atomicAdd(counter, 1u);
        lastFlag = (prev == (unsigned int)(BB - 1)) ? 1 : 0;
    }
    __syncthreads();
    if (!lastFlag) return;

    // ---- last block: merge 16 candidates/batch + beam-state update
    {
        int b = tid;
        int bi = b >> 2, r = b & 3;
        float vv = 0.0f; int flat = 0, p = 0, tok = 0, oldfin = 0;
        int col[TSTEPS + 1];
        bool act = (tid < 64);
        if (act) {
            float cv[16]; int ci[16];
            #pragma unroll
            for (int c = 0; c < 16; c++) {
                cv[c] = __uint_as_float(atomicAdd((unsigned int*)&rcv[bi * 16 + c], 0u));
                ci[c] = (int)atomicAdd((unsigned int*)&rci[bi * 16 + c], 0u);
            }
            int sel = 0;
            #pragma unroll
            for (int c = 0; c < 16; c++) {
                int rank = 0;
                #pragma unroll
                for (int d = 0; d < 16; d++)
                    if (d != c && better(cv[d], ci[d], cv[c], ci[c])) rank++;
                if (rank == r) sel = c;
            }
            vv = cv[sel];
            flat = ci[sel];
            int q = flat / VV;
            p = q + bi * 4;
            tok = flat - q * VV;
            oldfin = fin[p];
            #pragma unroll
            for (int rr = 0; rr <= TSTEPS; rr++) col[rr] = bo[rr * BB + p];
        }
        __syncthreads();
        if (act) {
            #pragma unroll
            for (int rr = 0; rr <= TSTEPS; rr++) bo[rr * BB + b] = col[rr];
            bo[(t + 1) * BB + b] = tok;
            ((int*)fin)[b] = oldfin | (tok == EOSTOK);
            ((float*)lp)[b] = vv;
            tokens[b] = tok;
            pidx[b]   = p;
        }
        __syncthreads();
        if (tid == 0) atomicExch(counter, 0u);   // rearm for next step
    }
}

// ---------------------------------------------------------------- final beam_out -> float
__global__ void final_kernel(const int* __restrict__ bo, float* __restrict__ out)
{
    int i = blockIdx.x * blockDim.x + threadIdx.x;
    if (i < (TSTEPS + 1) * BB) out[i] = (float)bo[i];
}

// ---------------------------------------------------------------- host
extern "C" void kernel_launch(void* const* d_in, const int* in_sizes, int n_in,
                              void* d_out, int out_size, void* d_ws, size_t ws_size,
                              hipStream_t stream)
{
    const int*   inputs = (const int*)d_in[0];
    const float* h0   = (const float*)d_in[1];
    const float* c0   = (const float*)d_in[2];
    const float* emb  = (const float*)d_in[3];
    const float* Wih0 = (const float*)d_in[4];
    const float* Whh0 = (const float*)d_in[5];
    const float* b0   = (const float*)d_in[6];
    const float* Wih1 = (const float*)d_in[7];
    const float* Whh1 = (const float*)d_in[8];
    const float* b1   = (const float*)d_in[9];
    const float* Wp   = (const float*)d_in[10];
    const float* bp   = (const float*)d_in[11];
    float* out = (float*)d_out;

    char* w = (char*)d_ws;
    size_t off = 0;
    auto alloc = [&](size_t bytes) { void* p = w + off; off += (bytes + 255) & ~255ULL; return p; };
    float* h0s[2], *c0s[2], *h1s[2], *c1s[2];
    for (int s = 0; s < 2; s++) {
        h0s[s] = (float*)alloc(BB * DD * 4);
        c0s[s] = (float*)alloc(BB * DD * 4);
        h1s[s] = (float*)alloc(BB * DD * 4);
        c1s[s] = (float*)alloc(BB * DD * 4);
    }
    float* rcv   = (float*)alloc(BB * 4 * 4);
    int*   rci   = (int*)alloc(BB * 4 * 4);
    float* lp    = (float*)alloc(BB * 4);
    int* pidx    = (int*)alloc(BB * 4);
    int* tokens  = (int*)alloc(BB * 4);
    int* fin     = (int*)alloc(BB * 4);
    int* bo      = (int*)alloc((TSTEPS + 1) * BB * 4);
    unsigned int* counter = (unsigned int*)alloc(256);

    init_kernel<<<128, 256, 0, stream>>>(inputs, h0, c0,
                                         h0s[0], c0s[0], h1s[0], c1s[0],
                                         tokens, pidx, fin, lp, bo, counter);

    for (int t = 0; t < TSTEPS; t++) {
        int s = t & 1, d2 = s ^ 1;
        lstm_kernel<<<1024, 128, 0, stream>>>(emb, tokens, h0s[s], c0s[s], pidx,
                                              h0s[d2], c0s[d2], Wih0, Whh0, b0);
        lstm_kernel<<<1024, 128, 0, stream>>>(h0s[d2], nullptr, h1s[s], c1s[s], pidx,
                                              h1s[d2], c1s[d2], Wih1, Whh1, b1);

        float* outf = out + (size_t)t * BB * VV;
        proj_kernel<<<NVT, 256, 0, stream>>>(h1s[d2], Wp, bp, outf);
        row_kernel<<<BB, 1024, 0, stream>>>(outf, lp, fin, rcv, rci,
                                            tokens, pidx, bo, counter, t);
    }
    final_kernel<<<5, 256, 0, stream>>>(bo, out + (size_t)TSTEPS * BB * VV);
}

// Round 18
// 2696.756 us; speedup vs baseline: 1.0814x; 1.0041x over previous
//
#include <hip/hip_runtime.h>
#include <math.h>

#define BS     16
#define NB     4
#define BB     64      // BS*NB
#define DD     512
#define VV     32000
#define TSTEPS 16
#define EOSTOK 2
#define NEGF   (-1e32f)
#define VT     64
#define NVT    (VV / VT)   // 500

__device__ __forceinline__ bool better(float av, int ai, float bv, int bi_) {
    return (av > bv) || (av == bv && ai < bi_);
}

// async global->LDS staging, no VGPR round-trip (gfx950)
__device__ __forceinline__ void glds4(const float* src, float* dst) {
    __builtin_amdgcn_global_load_lds((const __attribute__((address_space(1))) void*)src,
                                     (__attribute__((address_space(3))) void*)dst, 4, 0, 0);
}
__device__ __forceinline__ void glds16(const float* src, float* dst) {
    __builtin_amdgcn_global_load_lds((const __attribute__((address_space(1))) void*)src,
                                     (__attribute__((address_space(3))) void*)dst, 16, 0, 0);
}

// ---------------------------------------------------------------- init (fp32 states)
__global__ void init_kernel(const int* __restrict__ inputs,
                            const float* __restrict__ h0, const float* __restrict__ c0,
                            float* __restrict__ h0s, float* __restrict__ c0s,
                            float* __restrict__ h1s, float* __restrict__ c1s,
                            int* __restrict__ tokens, int* __restrict__ pidx,
                            int* __restrict__ fin, float* __restrict__ lp,
                            int* __restrict__ bo, unsigned int* __restrict__ counter)
{
    int tid = blockIdx.x * blockDim.x + threadIdx.x;
    int total = BB * DD;
    for (int i = tid; i < total; i += gridDim.x * blockDim.x) {
        int b = i / DD;
        int d = i % DD;
        int src0 = 0 * BS * DD + (b >> 2) * DD + d;
        int src1 = 1 * BS * DD + (b >> 2) * DD + d;
        h0s[i] = h0[src0];
        c0s[i] = c0[src0];
        h1s[i] = h0[src1];
        c1s[i] = c0[src1];
    }
    if (tid == 0) *counter = 0u;
    if (tid < BB) {
        tokens[tid] = inputs[tid >> 2];
        pidx[tid]   = tid;
        fin[tid]    = 0;
        lp[tid]     = 0.0f;
        bo[0 * BB + tid] = inputs[tid >> 2];
        for (int r = 1; r <= TSTEPS; r++) bo[r * BB + tid] = 0;
    }
}

// ---------------------------------------------------------------- LSTM: beam-split blocks + reg prefetch
// 1024 blocks x 128 threads; block = (j = bid>>1, beam-half = bid&1).
// Inner loop: 2-deep register prefetch of U quad + W float4; FMA order unchanged (bitwise-identical).
__global__ __launch_bounds__(128, 2) void lstm_kernel(
    const float* __restrict__ xbase, const int* __restrict__ xrow,
    const float* __restrict__ hsrc,  const float* __restrict__ csrc,
    const int* __restrict__ prow,
    float* __restrict__ hdst, float* __restrict__ cdst,
    const float* __restrict__ Wih, const float* __restrict__ Whh,
    const float* __restrict__ bias)
{
    __shared__ float U[32][129];
    __shared__ float Wl[4][1024];
    __shared__ double Z[4][32];
    __shared__ int rows_s[32], prows_s[32];
    int tid = threadIdx.x;
    int j  = blockIdx.x >> 1;
    int bo_ = (blockIdx.x & 1) * 32;
    int b = tid & 31;
    int g = tid >> 5;
    int lane = tid & 63;
    int w = tid >> 6;

    #pragma unroll
    for (int i = 0; i < 8; i++) {
        int s0 = (i * 2 + w) * 64;
        int gg = s0 >> 8;
        int hh = (s0 >> 7) & 1;
        int c0 = s0 & 127;
        const float* rowbase = (hh ? Whh : Wih) + (size_t)(gg * DD + j) * DD;
        glds16(rowbase + 4 * (c0 + lane), (float*)Wl + 4 * s0);
    }
    if (tid < 32) {
        rows_s[tid]  = xrow ? xrow[bo_ + tid] : (bo_ + tid);
        prows_s[tid] = prow[bo_ + tid];
    }

    double a0 = 0.0, a1 = 0.0, a2 = 0.0, a3 = 0.0;
    for (int ch = 0; ch < 8; ch++) {
        int k0 = ch * 128;
        __syncthreads();
        #pragma unroll
        for (int i = 0; i < 32; i++) {
            int s = i * 2 + w;
            int bb = s >> 1;
            int kk0 = (s & 1) * 64;
            const float* src;
            if (k0 < 512) src = xbase + (size_t)rows_s[bb] * DD + k0 + kk0 + lane;
            else          src = hsrc + (size_t)prows_s[bb] * DD + (k0 - 512) + kk0 + lane;
            glds4(src, &U[bb][kk0]);
        }
        __syncthreads();
        const float* Ub   = &U[b][0];
        const float* Wrow = &Wl[g][k0];
        float u0 = Ub[0], u1 = Ub[1], u2 = Ub[2], u3 = Ub[3];
        float4 wv = *(const float4*)&Wrow[0];
        #pragma unroll
        for (int kk = 0; kk < 128; kk += 4) {
            float n0 = 0.f, n1 = 0.f, n2 = 0.f, n3 = 0.f;
            float4 wn = {0.f, 0.f, 0.f, 0.f};
            if (kk < 124) {
                n0 = Ub[kk + 4]; n1 = Ub[kk + 5]; n2 = Ub[kk + 6]; n3 = Ub[kk + 7];
                wn = *(const float4*)&Wrow[kk + 4];
            }
            a0 = fma((double)u0, (double)wv.x, a0);
            a1 = fma((double)u1, (double)wv.y, a1);
            a2 = fma((double)u2, (double)wv.z, a2);
            a3 = fma((double)u3, (double)wv.w, a3);
            u0 = n0; u1 = n1; u2 = n2; u3 = n3; wv = wn;
        }
    }
    Z[g][b] = ((a0 + a1) + (a2 + a3));
    __syncthreads();

    if (tid < 32) {
        int gb = bo_ + b;
        double zi = Z[0][b] + (double)bias[0 * DD + j];
        double zf = Z[1][b] + (double)bias[1 * DD + j];
        double zg = Z[2][b] + (double)bias[2 * DD + j];
        double zo = Z[3][b] + (double)bias[3 * DD + j];
        double si = 1.0 / (1.0 + exp(-zi));
        double sf = 1.0 / (1.0 + exp(-zf));
        double so = 1.0 / (1.0 + exp(-zo));
        double cold = (double)csrc[(size_t)prows_s[b] * DD + j];
        double cn = sf * cold + si * tanh(zg);
        double hn = so * tanh(cn);
        hdst[gb * DD + j] = (float)hn;   // fp32 boundary
        cdst[gb * DD + j] = (float)cn;
    }
}

// ---------------------------------------------------------------- projection GEMM, full K + k4 reg-prefetch
// grid 500, 256 threads, thread tile 4b x 4v, fp64 acc over K=512. FMA order
// (ascending k4, same i/kk/q order) bitwise-identical to R17.
__global__ __launch_bounds__(256, 2) void proj_kernel(
    const float* __restrict__ h1, const float* __restrict__ Wp,
    const float* __restrict__ bp, float* __restrict__ outf)
{
    __shared__ float sh[64][68];    // [b][k-chunk]
    __shared__ float sw[64][68];    // [k-chunk][v]
    int vbase = blockIdx.x * VT;
    int tid = threadIdx.x;
    int lane = tid & 63;
    int w = tid >> 6;
    int b0 = (tid >> 4) * 4;
    int v0 = (tid & 15) * 4;

    double acc[4][4];
    #pragma unroll
    for (int i = 0; i < 4; i++)
        #pragma unroll
        for (int q = 0; q < 4; q++) acc[i][q] = 0.0;

    for (int ch = 0; ch < 8; ch++) {
        int k0 = ch * 64;
        __syncthreads();
        #pragma unroll
        for (int i = 0; i < 16; i++) {
            int bb = i * 4 + w;
            glds4(h1 + (size_t)bb * DD + k0 + lane, &sh[bb][0]);
        }
        #pragma unroll
        for (int i = 0; i < 16; i++) {
            int kk = i * 4 + w;
            glds4(Wp + (size_t)(k0 + kk) * VV + vbase + lane, &sw[kk][0]);
        }
        __syncthreads();

        float4 h4a[4], w4a[4], h4b[4], w4b[4];
        #pragma unroll
        for (int i = 0; i < 4; i++) h4a[i] = *(const float4*)&sh[b0 + i][0];
        #pragma unroll
        for (int kk = 0; kk < 4; kk++) w4a[kk] = *(const float4*)&sw[kk][v0];

        #pragma unroll
        for (int k8 = 0; k8 < 8; k8++) {
            int ka = k8 * 8;        // slice done from slot A
            int kb = ka + 4;        // slice done from slot B
            // prefetch kb into B
            #pragma unroll
            for (int i = 0; i < 4; i++) h4b[i] = *(const float4*)&sh[b0 + i][kb];
            #pragma unroll
            for (int kk = 0; kk < 4; kk++) w4b[kk] = *(const float4*)&sw[kb + kk][v0];
            // FMA slot A (slice ka)
            #pragma unroll
            for (int i = 0; i < 4; i++) {
                const float hh[4] = {h4a[i].x, h4a[i].y, h4a[i].z, h4a[i].w};
                #pragma unroll
                for (int kk = 0; kk < 4; kk++) {
                    double hd = (double)hh[kk];
                    const float ww[4] = {w4a[kk].x, w4a[kk].y, w4a[kk].z, w4a[kk].w};
                    #pragma unroll
                    for (int q = 0; q < 4; q++)
                        acc[i][q] = fma(hd, (double)ww[q], acc[i][q]);
                }
            }
            // prefetch next A (slice kb+4), if any
            if (k8 < 7) {
                int kn = kb + 4;
                #pragma unroll
                for (int i = 0; i < 4; i++) h4a[i] = *(const float4*)&sh[b0 + i][kn];
                #pragma unroll
                for (int kk = 0; kk < 4; kk++) w4a[kk] = *(const float4*)&sw[kn + kk][v0];
            }
            // FMA slot B (slice kb)
            #pragma unroll
            for (int i = 0; i < 4; i++) {
                const float hh[4] = {h4b[i].x, h4b[i].y, h4b[i].z, h4b[i].w};
                #pragma unroll
                for (int kk = 0; kk < 4; kk++) {
                    double hd = (double)hh[kk];
                    const float ww[4] = {w4b[kk].x, w4b[kk].y, w4b[kk].z, w4b[kk].w};
                    #pragma unroll
                    for (int q = 0; q < 4; q++)
                        acc[i][q] = fma(hd, (double)ww[q], acc[i][q]);
                }
            }
        }
    }

    #pragma unroll
    for (int i = 0; i < 4; i++) {
        int brow = b0 + i;
        #pragma unroll
        for (int q = 0; q < 4; q++) {
            int v = vbase + v0 + q;
            outf[(size_t)brow * VV + v] = (float)(acc[i][q] + (double)bp[v]);  // fp32 boundary
        }
    }
}

// ---------------------------------------------------------------- fused LSE + row top-4 + last-block merge
#define NPT 32   // ceil(32000/1024)
__global__ __launch_bounds__(1024) void row_kernel(
    const float* __restrict__ outf, const float* __restrict__ lp,
    const int* __restrict__ fin,
    float* __restrict__ rcv, int* __restrict__ rci,
    int* __restrict__ tokens, int* __restrict__ pidx, int* __restrict__ bo,
    unsigned int* __restrict__ counter, int t)
{
    int step0 = (t == 0) ? 1 : 0;
    int row = blockIdx.x;
    int j   = row & 3;
    int tid = threadIdx.x;
    int base_idx = j * VV;

    __shared__ float winv[4];
    __shared__ int   win[4];
    __shared__ double red[1024];

    float lp_r = step0 ? 0.0f : lp[row];
    int   f    = step0 ? 0    : fin[row];

    bool trivial = (step0 && j != 0) || (!step0 && f);
    if (trivial) {
        if (tid < 4) {
            winv[tid] = ((!step0 && f) && tid == 0) ? lp_r : NEGF;
            win[tid]  = base_idx + tid;
        }
    } else {
        const float* xo = outf + (size_t)row * VV;

        float zreg[NPT];
        double m = -1e300;
        #pragma unroll
        for (int q = 0; q < NPT; q++) {
            int i = tid + q * 1024;
            float zf = 0.0f;
            if (i < VV) {
                zf = xo[i];
                m = fmax(m, (double)zf);
            }
            zreg[q] = zf;
        }

        red[tid] = m; __syncthreads();
        for (int s = 512; s > 0; s >>= 1) {
            if (tid < s) red[tid] = fmax(red[tid], red[tid + s]);
            __syncthreads();
        }
        m = red[0];
        __syncthreads();

        double sum = 0.0;
        #pragma unroll
        for (int q = 0; q < NPT; q++) {
            int i = tid + q * 1024;
            if (i < VV) sum += exp((double)zreg[q] - m);
        }
        red[tid] = sum; __syncthreads();
        for (int s = 512; s > 0; s >>= 1) {
            if (tid < s) red[tid] += red[tid + s];
            __syncthreads();
        }
        double lse = m + log(red[0]);
        __syncthreads();

        float bv[4]; int bx[4];
        #pragma unroll
        for (int q = 0; q < 4; q++) { bv[q] = -3.4e38f; bx[q] = 0x7fffffff; }
        #pragma unroll
        for (int q = 0; q < NPT; q++) {
            int i = tid + q * 1024;
            if (i < VV) {
                float lgp32 = (float)((double)zreg[q] - lse);
                float val   = (float)((double)lp_r + (double)lgp32);
                int idx = base_idx + i;
                if (better(val, idx, bv[3], bx[3])) {
                    bv[3] = val; bx[3] = idx;
                    #pragma unroll
                    for (int s = 3; s > 0; s--) {
                        if (better(bv[s], bx[s], bv[s - 1], bx[s - 1])) {
                            float tv2 = bv[s]; bv[s] = bv[s - 1]; bv[s - 1] = tv2;
                            int ti2 = bx[s]; bx[s] = bx[s - 1]; bx[s - 1] = ti2;
                        }
                    }
                }
            }
        }

        __shared__ float sv[1024][4];
        __shared__ int   si_[1024][4];
        #pragma unroll
        for (int q = 0; q < 4; q++) { sv[tid][q] = bv[q]; si_[tid][q] = bx[q]; }
        __syncthreads();
        for (int s = 512; s > 0; s >>= 1) {
            if (tid < s) {
                float av[4], ov[4], mv[4]; int ai[4], oi[4], mi[4];
                #pragma unroll
                for (int q = 0; q < 4; q++) {
                    av[q] = sv[tid][q];     ai[q] = si_[tid][q];
                    ov[q] = sv[tid + s][q]; oi[q] = si_[tid + s][q];
                }
                int pa = 0, pb = 0;
                #pragma unroll
                for (int q = 0; q < 4; q++) {
                    bool takeA = (pb >= 4) || (pa < 4 && better(av[pa], ai[pa], ov[pb], oi[pb]));
                    if (takeA) { mv[q] = av[pa]; mi[q] = ai[pa]; pa++; }
                    else       { mv[q] = ov[pb]; mi[q] = oi[pb]; pb++; }
                }
                #pragma unroll
                for (int q = 0; q < 4; q++) { sv[tid][q] = mv[q]; si_[tid][q] = mi[q]; }
            }
            __syncthreads();
        }
        if (tid < 4) { winv[tid] = sv[0][tid]; win[tid] = si_[0][tid]; }
    }
    __syncthreads();

    // publish candidates (device-scope atomics: cross-XCD coherent)
    if (tid < 4) {
        atomicExch((unsigned int*)&rcv[row * 4 + tid], __float_as_uint(winv[tid]));
        atomicExch((unsigned int*)&rci[row * 4 + tid], (unsigned int)win[tid]);
        __threadfence();
    }
    __syncthreads();

    __shared__ int lastFlag;
    if (tid == 0) {
        unsigned int prev = atomicAdd(counter, 1u);
        lastFlag = (prev == (unsigned int)(BB - 1)) ? 1 : 0;
    }
    __syncthreads();
    if (!lastFlag) return;

    // last block: merge 16 candidates/batch + beam-state update
    {
        int b = tid;
        int bi = b >> 2, r = b & 3;
        float vv = 0.0f; int flat = 0, p = 0, tok = 0, oldfin = 0;
        int col[TSTEPS + 1];
        bool act = (tid < 64);
        if (act) {
            float cv[16]; int ci[16];
            #pragma unroll
            for (int c = 0; c < 16; c++) {
                cv[c] = __uint_as_float(atomicAdd((unsigned int*)&rcv[bi * 16 + c], 0u));
                ci[c] = (int)atomicAdd((unsigned int*)&rci[bi * 16 + c], 0u);
            }
            int sel = 0;
            #pragma unroll
            for (int c = 0; c < 16; c++) {
                int rank = 0;
                #pragma unroll
                for (int d = 0; d < 16; d++)
                    if (d != c && better(cv[d], ci[d], cv[c], ci[c])) rank++;
                if (rank == r) sel = c;
            }
            vv = cv[sel];
            flat = ci[sel];
            int q = flat / VV;
            p = q + bi * 4;
            tok = flat - q * VV;
            oldfin = fin[p];
            #pragma unroll
            for (int rr = 0; rr <= TSTEPS; rr++) col[rr] = bo[rr * BB + p];
        }
        __syncthreads();
        if (act) {
            #pragma unroll
            for (int rr = 0; rr <= TSTEPS; rr++) bo[rr * BB + b] = col[rr];
            bo[(t + 1) * BB + b] = tok;
            ((int*)fin)[b] = oldfin | (tok == EOSTOK);
            ((float*)lp)[b] = vv;
            tokens[b] = tok;
            pidx[b]   = p;
        }
        __syncthreads();
        if (tid == 0) atomicExch(counter, 0u);   // rearm for next step
    }
}

// ---------------------------------------------------------------- final beam_out -> float
__global__ void final_kernel(const int* __restrict__ bo, float* __restrict__ out)
{
    int i = blockIdx.x * blockDim.x + threadIdx.x;
    if (i < (TSTEPS + 1) * BB) out[i] = (float)bo[i];
}

// ---------------------------------------------------------------- host
extern "C" void kernel_launch(void* const* d_in, const int* in_sizes, int n_in,
                              void* d_out, int out_size, void* d_ws, size_t ws_size,
                              hipStream_t stream)
{
    const int*   inputs = (const int*)d_in[0];
    const float* h0   = (const float*)d_in[1];
    const float* c0   = (const float*)d_in[2];
    const float* emb  = (const float*)d_in[3];
    const float* Wih0 = (const float*)d_in[4];
    const float* Whh0 = (const float*)d_in[5];
    const float* b0   = (const float*)d_in[6];
    const float* Wih1 = (const float*)d_in[7];
    const float* Whh1 = (const float*)d_in[8];
    const float* b1   = (const float*)d_in[9];
    const float* Wp   = (const float*)d_in[10];
    const float* bp   = (const float*)d_in[11];
    float* out = (float*)d_out;

    char* w = (char*)d_ws;
    size_t off = 0;
    auto alloc = [&](size_t bytes) { void* p = w + off; off += (bytes + 255) & ~255ULL; return p; };
    float* h0s[2], *c0s[2], *h1s[2], *c1s[2];
    for (int s = 0; s < 2; s++) {
        h0s[s] = (float*)alloc(BB * DD * 4);
        c0s[s] = (float*)alloc(BB * DD * 4);
        h1s[s] = (float*)alloc(BB * DD * 4);
        c1s[s] = (float*)alloc(BB * DD * 4);
    }
    float* rcv   = (float*)alloc(BB * 4 * 4);
    int*   rci   = (int*)alloc(BB * 4 * 4);
    float* lp    = (float*)alloc(BB * 4);
    int* pidx    = (int*)alloc(BB * 4);
    int* tokens  = (int*)alloc(BB * 4);
    int* fin     = (int*)alloc(BB * 4);
    int* bo      = (int*)alloc((TSTEPS + 1) * BB * 4);
    unsigned int* counter = (unsigned int*)alloc(256);

    init_kernel<<<128, 256, 0, stream>>>(inputs, h0, c0,
                                         h0s[0], c0s[0], h1s[0], c1s[0],
                                         tokens, pidx, fin, lp, bo, counter);

    for (int t = 0; t < TSTEPS; t++) {
        int s = t & 1, d2 = s ^ 1;
        lstm_kernel<<<1024, 128, 0, stream>>>(emb, tokens, h0s[s], c0s[s], pidx,
                                              h0s[d2], c0s[d2], Wih0, Whh0, b0);
        lstm_kernel<<<1024, 128, 0, stream>>>(h0s[d2], nullptr, h1s[s], c1s[s], pidx,
                                              h1s[d2], c1s[d2], Wih1, Whh1, b1);

        float* outf = out + (size_t)t * BB * VV;
        proj_kernel<<<NVT, 256, 0, stream>>>(h1s[d2], Wp, bp, outf);
        row_kernel<<<BB, 1024, 0, stream>>>(outf, lp, fin, rcv, rci,
                                            tokens, pidx, bo, counter, t);
    }
    final_kernel<<<5, 256, 0, stream>>>(bo, out + (size_t)TSTEPS * BB * VV);
}